// Round 1
// baseline (471.254 us; speedup 1.0000x reference)
//
#include <hip/hip_runtime.h>

typedef float f32x4 __attribute__((ext_vector_type(4)));
typedef short s16x8 __attribute__((ext_vector_type(8)));

#define NN 4096
#define NB 32
#define DIN 64
#define DH 128
#define DOUT 32
#define DIM 40

__device__ __forceinline__ unsigned short f2bf(float f) {
    unsigned int u = __float_as_uint(f);
    unsigned int r = (u + 0x7FFFu + ((u >> 16) & 1u)) >> 16;
    return (unsigned short)r;
}
__device__ __forceinline__ float bf2f(unsigned short h) {
    return __uint_as_float(((unsigned int)h) << 16);
}
__device__ __forceinline__ void gload16(const void* g, void* l) {
    __builtin_amdgcn_global_load_lds(
        (const __attribute__((address_space(1))) unsigned int*)g,
        (__attribute__((address_space(3))) unsigned int*)l, 16, 0, 0);
}

// ---------------- stage 1: n1/n2 = tanh(3*(emb @ W + b)) ----------------
__global__ __launch_bounds__(256) void k_embed(
    const float* __restrict__ emb1, const float* __restrict__ emb2,
    const float* __restrict__ l1w, const float* __restrict__ l1b,
    const float* __restrict__ l2w, const float* __restrict__ l2b,
    float* __restrict__ n1, float* __restrict__ n2)
{
    __shared__ float w1s[DIM * DIM], w2s[DIM * DIM], b1s[DIM], b2s[DIM];
    int tid = threadIdx.x;
    for (int i = tid; i < DIM * DIM; i += 256) { w1s[i] = l1w[i]; w2s[i] = l2w[i]; }
    if (tid < DIM) { b1s[tid] = l1b[tid]; b2s[tid] = l2b[tid]; }
    __syncthreads();
    int t = blockIdx.x * 256 + tid;          // < 2*4096*40 = 327680
    int half = t >= NN * DIM;
    int r = t - half * (NN * DIM);
    int i = r / DIM, c = r - i * DIM;
    const float* emb = half ? emb2 : emb1;
    const float* ws  = half ? w2s : w1s;
    float acc = half ? b2s[c] : b1s[c];
    for (int k = 0; k < DIM; k++) acc += emb[i * DIM + k] * ws[k * DIM + c];
    (half ? n2 : n1)[r] = tanhf(3.0f * acc);
}

// ---------------- stage 2: adjacency bits + degree ----------------
// MTbits[j][i/32] bit(i&31) = M[i][j] = (i==j) || (s[i][j] > s[j][i])
__global__ __launch_bounds__(256) void k_adj(
    const float* __restrict__ n1, const float* __restrict__ n2,
    unsigned int* __restrict__ mtb, int* __restrict__ deg)
{
    __shared__ float s_n1i[64][41], s_n2i[64][41], s_n1j[64][41], s_n2j[64][41];
    int i0 = blockIdx.x * 64, j0 = blockIdx.y * 64;
    int tid = threadIdx.x;
    for (int idx = tid; idx < 64 * DIM; idx += 256) {
        int r = idx / DIM, c = idx - r * DIM;
        s_n1i[r][c] = n1[(i0 + r) * DIM + c];
        s_n2i[r][c] = n2[(i0 + r) * DIM + c];
        s_n1j[r][c] = n1[(j0 + r) * DIM + c];
        s_n2j[r][c] = n2[(j0 + r) * DIM + c];
    }
    __syncthreads();
    int lane = tid & 63, w = tid >> 6;
    int i = i0 + lane;
    for (int jj = w; jj < 64; jj += 4) {
        int j = j0 + jj;
        float d1 = 0.f, d2 = 0.f;
        #pragma unroll
        for (int k = 0; k < DIM; k++) {
            d1 += s_n1i[lane][k] * s_n2j[jj][k];   // s[i][j]
            d2 += s_n1j[jj][k] * s_n2i[lane][k];   // s[j][i]
        }
        bool bit = (i == j) || (d1 > d2);
        unsigned long long mask = __ballot(bit);
        if (lane == 0) {
            mtb[(size_t)j * 128 + (i0 >> 5)]     = (unsigned int)mask;
            mtb[(size_t)j * 128 + (i0 >> 5) + 1] = (unsigned int)(mask >> 32);
            atomicAdd(&deg[j], (int)__popcll(mask));
        }
    }
}

__global__ void k_dinv(const int* __restrict__ deg, float* __restrict__ dinv) {
    int i = blockIdx.x * 256 + threadIdx.x;
    if (i < NN) dinv[i] = 1.0f / sqrtf((float)deg[i]);
}

// bits -> bf16 0/1 matrix MT[j][i]
__global__ __launch_bounds__(256) void k_expand(
    const unsigned int* __restrict__ mtb, unsigned short* __restrict__ MT)
{
    int idx = blockIdx.x * 256 + threadIdx.x;   // < 4096*128
    unsigned int bits = mtb[idx];
    size_t base = (size_t)idx * 32;
    #pragma unroll
    for (int q = 0; q < 4; q++) {
        s16x8 v;
        #pragma unroll
        for (int e = 0; e < 8; e++)
            v[e] = (short)(((bits >> (q * 8 + e)) & 1u) ? 0x3F80 : 0);
        *(s16x8*)(MT + base + q * 8) = v;
    }
}

// ---------------- YT[c=b*128+f][i] = bf16( dinv_i * (x[b,i,:] @ W1[:,f]) ) ----------------
__global__ __launch_bounds__(256) void k_y1(
    const float* __restrict__ x, const float* __restrict__ W1,
    const float* __restrict__ dinv, unsigned short* __restrict__ YT)
{
    __shared__ __align__(16) float xs[128][DIN];
    __shared__ __align__(16) float w1s[DIN][DH];
    int i0 = blockIdx.x * 128, b = blockIdx.y;
    int tid = threadIdx.x;
    const f32x4* xg = (const f32x4*)(x + ((size_t)(b * NN + i0)) * DIN);
    #pragma unroll
    for (int q = 0; q < 8; q++) {               // 128*16 f32x4
        int idx = q * 256 + tid;
        int row = idx >> 4, c4 = idx & 15;
        *(f32x4*)&xs[row][c4 * 4] = xg[(size_t)row * 16 + c4];
    }
    #pragma unroll
    for (int q = 0; q < 8; q++) {               // 64*32 f32x4
        int idx = q * 256 + tid;
        int row = idx >> 5, c4 = idx & 31;
        *(f32x4*)&w1s[row][c4 * 4] = ((const f32x4*)W1)[idx];
    }
    __syncthreads();
    int tf = tid & 15, ti = tid >> 4;
    f32x4 t0[8] = {}, t1[8] = {};
    for (int k4 = 0; k4 < DIN; k4 += 4) {
        f32x4 xv[8];
        #pragma unroll
        for (int ii = 0; ii < 8; ii++) xv[ii] = *(const f32x4*)&xs[ti * 8 + ii][k4];
        #pragma unroll
        for (int kk = 0; kk < 4; kk++) {
            f32x4 w0 = *(const f32x4*)&w1s[k4 + kk][tf * 8];
            f32x4 w1v = *(const f32x4*)&w1s[k4 + kk][tf * 8 + 4];
            #pragma unroll
            for (int ii = 0; ii < 8; ii++) {
                float s = xv[ii][kk];
                t0[ii] += s * w0;
                t1[ii] += s * w1v;
            }
        }
    }
    float dvv[8];
    #pragma unroll
    for (int ii = 0; ii < 8; ii++) dvv[ii] = dinv[i0 + ti * 8 + ii];
    #pragma unroll
    for (int ff = 0; ff < 8; ff++) {
        s16x8 pk;
        #pragma unroll
        for (int ii = 0; ii < 8; ii++) {
            float v = (ff < 4 ? t0[ii][ff] : t1[ii][ff - 4]) * dvv[ii];
            pk[ii] = (short)f2bf(v);
        }
        *(s16x8*)(YT + ((size_t)(b * DH + tf * 8 + ff)) * NN + i0 + ti * 8) = pk;
    }
}

// ---------------- GEMM: C[j][c] = sum_i A[j][i] * Bt[c][i], m97 structure ----------------
// MODE 0: out bf16 = relu(dinv_j*acc + bias[c&bmask]);  MODE 1: out f32 = dinv_j*acc + bias
template <int MODE>
__global__ __launch_bounds__(256) void gemm_mt(
    const unsigned short* __restrict__ A, const unsigned short* __restrict__ Bt,
    void* __restrict__ out, const float* __restrict__ dinv,
    const float* __restrict__ bias, int bmask, int M, int N, int K)
{
    constexpr int BM = 128, BN = 128, BK = 64;
    __shared__ __align__(16) unsigned short Asm[BM * BK];
    __shared__ __align__(16) unsigned short Bsm[BN * BK];
    const int tid = threadIdx.x;
    const int lane = tid & 63;
    const int w = tid >> 6;          // wave 0..3
    const int wm = w >> 1, wn = w & 1;
    const int c0 = blockIdx.x * BN;
    const int j0 = blockIdx.y * BM;

    // staging: 1024 chunks of 16B per tile; chunk cid -> row=cid>>3, kc=cid&7.
    // LDS is linear; global source is pre-swizzled: kchunk_src = kc ^ (row&7).
    int srcOff[4];
    #pragma unroll
    for (int q = 0; q < 4; q++) {
        int cid = w * 256 + q * 64 + lane;
        int row = cid >> 3, kc = cid & 7;
        srcOff[q] = row * K + ((kc ^ (row & 7)) << 3);   // ushort units
    }
    const int fr = lane & 15;   // frag row (A) / col (B)
    const int kg = lane >> 4;   // k-group

    f32x4 acc[4][4] = {};
    const unsigned short* Abase = A + (size_t)j0 * K;
    const unsigned short* Bbase = Bt + (size_t)c0 * K;

    for (int kt = 0; kt < K; kt += BK) {
        __syncthreads();
        const unsigned short* Ag = Abase + kt;
        const unsigned short* Bg = Bbase + kt;
        #pragma unroll
        for (int q = 0; q < 4; q++)
            gload16(Ag + srcOff[q], &Asm[(w * 256 + q * 64) * 8]);
        #pragma unroll
        for (int q = 0; q < 4; q++)
            gload16(Bg + srcOff[q], &Bsm[(w * 256 + q * 64) * 8]);
        __syncthreads();

        s16x8 af[2][4], bf[2][4];
        #pragma unroll
        for (int ks = 0; ks < 2; ks++) {
            int kc = ks * 4 + kg;       // chunk of this frag's k
            #pragma unroll
            for (int m = 0; m < 4; m++) {
                int row = wm * 64 + m * 16 + fr;
                af[ks][m] = *(const s16x8*)((const char*)Asm + row * 128 + ((kc ^ (row & 7)) << 4));
            }
            #pragma unroll
            for (int n = 0; n < 4; n++) {
                int row = wn * 64 + n * 16 + fr;
                bf[ks][n] = *(const s16x8*)((const char*)Bsm + row * 128 + ((kc ^ (row & 7)) << 4));
            }
        }
        #pragma unroll
        for (int ks = 0; ks < 2; ks++)
            #pragma unroll
            for (int m = 0; m < 4; m++)
                #pragma unroll
                for (int n = 0; n < 4; n++)
                    acc[m][n] = __builtin_amdgcn_mfma_f32_16x16x32_bf16(
                        af[ks][m], bf[ks][n], acc[m][n], 0, 0, 0);
    }

    // epilogue: D row=(lane>>4)*4+r, col=lane&15 within each 16x16 frag
    #pragma unroll
    for (int m = 0; m < 4; m++) {
        int rbase = j0 + wm * 64 + m * 16 + kg * 4;
        float dv[4];
        #pragma unroll
        for (int r = 0; r < 4; r++) dv[r] = dinv[rbase + r];
        #pragma unroll
        for (int n = 0; n < 4; n++) {
            int gcol = c0 + wn * 64 + n * 16 + fr;
            float bb = bias[gcol & bmask];
            #pragma unroll
            for (int r = 0; r < 4; r++) {
                float v = acc[m][n][r] * dv[r] + bb;
                size_t off = (size_t)(rbase + r) * N + gcol;
                if (MODE == 0) {
                    v = v > 0.f ? v : 0.f;
                    ((unsigned short*)out)[off] = f2bf(v);
                } else {
                    ((float*)out)[off] = v;
                }
            }
        }
    }
}

// ---------------- ZT[c2=b*32+g][j] = bf16( dinv_j * (h[b,j,:] @ W2[:,g]) ) ----------------
__global__ __launch_bounds__(256) void k_z(
    const unsigned short* __restrict__ H, const float* __restrict__ W2,
    const float* __restrict__ dinv, unsigned short* __restrict__ ZT)
{
    __shared__ __align__(16) unsigned short Hs[128][136];
    __shared__ __align__(16) float w2s[DH][DOUT];
    int j0 = blockIdx.x * 128, b = blockIdx.y;
    int tid = threadIdx.x;
    #pragma unroll
    for (int q = 0; q < 8; q++) {               // 128*16 chunks
        int idx = q * 256 + tid;
        int row = idx >> 4, c = idx & 15;
        *(s16x8*)&Hs[row][c * 8] =
            *(const s16x8*)(H + (size_t)(j0 + row) * (NB * DH) + b * DH + c * 8);
    }
    #pragma unroll
    for (int q = 0; q < 4; q++) {               // 128*8 f32x4
        int idx = q * 256 + tid;
        int row = idx >> 3, c4 = idx & 7;
        *(f32x4*)&w2s[row][c4 * 4] = ((const f32x4*)W2)[idx];
    }
    __syncthreads();
    int g = tid & 31, jq = tid >> 5;
    #pragma unroll
    for (int t = 0; t < 2; t++) {
        int jb = (t * 8 + jq) * 8;
        float accz[8] = {};
        for (int f8 = 0; f8 < 16; f8++) {
            float wv[8];
            #pragma unroll
            for (int e = 0; e < 8; e++) wv[e] = w2s[f8 * 8 + e][g];
            #pragma unroll
            for (int jj = 0; jj < 8; jj++) {
                s16x8 hc = *(const s16x8*)&Hs[jb + jj][f8 * 8];
                #pragma unroll
                for (int e = 0; e < 8; e++)
                    accz[jj] += bf2f((unsigned short)hc[e]) * wv[e];
            }
        }
        s16x8 pk;
        #pragma unroll
        for (int jj = 0; jj < 8; jj++)
            pk[jj] = (short)f2bf(accz[jj] * dinv[j0 + jb + jj]);
        *(s16x8*)(ZT + (size_t)(b * DOUT + g) * NN + j0 + jb) = pk;
    }
}

// ---------------- softmax over g, scatter to output layout ----------------
__global__ __launch_bounds__(256) void k_softmax(
    const float* __restrict__ logits, float* __restrict__ out)
{
    int tid = threadIdx.x;
    int p = blockIdx.x * 8 + (tid >> 5);        // 0 .. 131071  (p = b*4096 + j)
    int b = p >> 12, j = p & 4095;
    int g = tid & 31;
    float v = logits[(size_t)j * (NB * DOUT) + b * DOUT + g];
    float m = v;
    #pragma unroll
    for (int d = 16; d; d >>= 1) m = fmaxf(m, __shfl_xor(m, d));
    float e = expf(v - m);
    float s = e;
    #pragma unroll
    for (int d = 16; d; d >>= 1) s += __shfl_xor(s, d);
    out[(size_t)p * DOUT + g] = e / s;
}

extern "C" void kernel_launch(void* const* d_in, const int* in_sizes, int n_in,
                              void* d_out, int out_size, void* d_ws, size_t ws_size,
                              hipStream_t stream)
{
    (void)in_sizes; (void)n_in; (void)out_size; (void)ws_size;
    const float* x    = (const float*)d_in[0];
    const float* emb1 = (const float*)d_in[1];
    const float* emb2 = (const float*)d_in[2];
    const float* l1w  = (const float*)d_in[3];
    const float* l1b  = (const float*)d_in[4];
    const float* l2w  = (const float*)d_in[5];
    const float* l2b  = (const float*)d_in[6];
    const float* g1w  = (const float*)d_in[7];
    const float* g1b  = (const float*)d_in[8];
    const float* g2w  = (const float*)d_in[9];
    const float* g2b  = (const float*)d_in[10];
    float* out = (float*)d_out;

    char* w = (char*)d_ws;
    float* n1 = (float*)w;                    w += NN * DIM * 4;
    float* n2 = (float*)w;                    w += NN * DIM * 4;
    int* deg = (int*)w;                       w += NN * 4;
    float* dinv = (float*)w;                  w += NN * 4;
    unsigned int* mtb = (unsigned int*)w;     w += (size_t)NN * 128 * 4;
    unsigned short* MT = (unsigned short*)w;  w += (size_t)NN * NN * 2;
    unsigned short* YT = (unsigned short*)w;  w += (size_t)NN * NN * 2;
    unsigned short* H  = (unsigned short*)w;  w += (size_t)NN * NN * 2;
    unsigned short* ZT = (unsigned short*)w;  w += (size_t)(NB * DOUT) * NN * 2;
    float* logits = (float*)YT;               // YT dead after gemm1; 16MB <= 32MB

    hipMemsetAsync(deg, 0, NN * sizeof(int), stream);
    k_embed<<<1280, 256, 0, stream>>>(emb1, emb2, l1w, l1b, l2w, l2b, n1, n2);
    k_adj<<<dim3(64, 64), 256, 0, stream>>>(n1, n2, mtb, deg);
    k_dinv<<<16, 256, 0, stream>>>(deg, dinv);
    k_expand<<<2048, 256, 0, stream>>>(mtb, MT);
    k_y1<<<dim3(32, 32), 256, 0, stream>>>(x, g1w, dinv, YT);
    gemm_mt<0><<<dim3(32, 32), 256, 0, stream>>>(MT, YT, (void*)H, dinv, g1b, 127,
                                                 NN, NB * DH, NN);
    k_z<<<dim3(32, 32), 256, 0, stream>>>(H, g2w, dinv, ZT);
    gemm_mt<1><<<dim3(8, 32), 256, 0, stream>>>(MT, ZT, (void*)logits, dinv, g2b, 31,
                                                NN, NB * DOUT, NN);
    k_softmax<<<16384, 256, 0, stream>>>(logits, out);
}

// Round 2
// 452.672 us; speedup vs baseline: 1.0410x; 1.0410x over previous
//
#include <hip/hip_runtime.h>

typedef float f32x4 __attribute__((ext_vector_type(4)));
typedef short s16x8 __attribute__((ext_vector_type(8)));

#define NN 4096
#define NB 32
#define DIN 64
#define DH 128
#define DOUT 32
#define DIM 40

__device__ __forceinline__ unsigned short f2bf(float f) {
    unsigned int u = __float_as_uint(f);
    unsigned int r = (u + 0x7FFFu + ((u >> 16) & 1u)) >> 16;
    return (unsigned short)r;
}
__device__ __forceinline__ float bf2f(unsigned short h) {
    return __uint_as_float(((unsigned int)h) << 16);
}
__device__ __forceinline__ void gload16(const void* g, void* l) {
    __builtin_amdgcn_global_load_lds(
        (const __attribute__((address_space(1))) unsigned int*)g,
        (__attribute__((address_space(3))) unsigned int*)l, 16, 0, 0);
}
__device__ __forceinline__ void bar() {
    asm volatile("" ::: "memory");
    __builtin_amdgcn_s_barrier();
    asm volatile("" ::: "memory");
}

// ---------------- stage 1: n1/n2 = tanh(3*(emb @ W + b)) ----------------
__global__ __launch_bounds__(256) void k_embed(
    const float* __restrict__ emb1, const float* __restrict__ emb2,
    const float* __restrict__ l1w, const float* __restrict__ l1b,
    const float* __restrict__ l2w, const float* __restrict__ l2b,
    float* __restrict__ n1, float* __restrict__ n2)
{
    __shared__ float w1s[DIM * DIM], w2s[DIM * DIM], b1s[DIM], b2s[DIM];
    int tid = threadIdx.x;
    for (int i = tid; i < DIM * DIM; i += 256) { w1s[i] = l1w[i]; w2s[i] = l2w[i]; }
    if (tid < DIM) { b1s[tid] = l1b[tid]; b2s[tid] = l2b[tid]; }
    __syncthreads();
    int t = blockIdx.x * 256 + tid;          // < 2*4096*40 = 327680
    int half = t >= NN * DIM;
    int r = t - half * (NN * DIM);
    int i = r / DIM, c = r - i * DIM;
    const float* emb = half ? emb2 : emb1;
    const float* ws  = half ? w2s : w1s;
    float acc = half ? b2s[c] : b1s[c];
    for (int k = 0; k < DIM; k++) acc += emb[i * DIM + k] * ws[k * DIM + c];
    (half ? n2 : n1)[r] = tanhf(3.0f * acc);
}

// ---------------- stage 2: adjacency bits + degree ----------------
__global__ __launch_bounds__(256) void k_adj(
    const float* __restrict__ n1, const float* __restrict__ n2,
    unsigned int* __restrict__ mtb, int* __restrict__ deg)
{
    __shared__ float s_n1i[64][41], s_n2i[64][41], s_n1j[64][41], s_n2j[64][41];
    int i0 = blockIdx.x * 64, j0 = blockIdx.y * 64;
    int tid = threadIdx.x;
    for (int idx = tid; idx < 64 * DIM; idx += 256) {
        int r = idx / DIM, c = idx - r * DIM;
        s_n1i[r][c] = n1[(i0 + r) * DIM + c];
        s_n2i[r][c] = n2[(i0 + r) * DIM + c];
        s_n1j[r][c] = n1[(j0 + r) * DIM + c];
        s_n2j[r][c] = n2[(j0 + r) * DIM + c];
    }
    __syncthreads();
    int lane = tid & 63, w = tid >> 6;
    int i = i0 + lane;
    for (int jj = w; jj < 64; jj += 4) {
        int j = j0 + jj;
        float d1 = 0.f, d2 = 0.f;
        #pragma unroll
        for (int k = 0; k < DIM; k++) {
            d1 += s_n1i[lane][k] * s_n2j[jj][k];   // s[i][j]
            d2 += s_n1j[jj][k] * s_n2i[lane][k];   // s[j][i]
        }
        bool bit = (i == j) || (d1 > d2);
        unsigned long long mask = __ballot(bit);
        if (lane == 0) {
            mtb[(size_t)j * 128 + (i0 >> 5)]     = (unsigned int)mask;
            mtb[(size_t)j * 128 + (i0 >> 5) + 1] = (unsigned int)(mask >> 32);
            atomicAdd(&deg[j], (int)__popcll(mask));
        }
    }
}

__global__ void k_dinv(const int* __restrict__ deg, float* __restrict__ dinv) {
    int i = blockIdx.x * 256 + threadIdx.x;
    if (i < NN) dinv[i] = 1.0f / sqrtf((float)deg[i]);
}

// bits -> bf16 0/1 matrix MT[j][i]
__global__ __launch_bounds__(256) void k_expand(
    const unsigned int* __restrict__ mtb, unsigned short* __restrict__ MT)
{
    int idx = blockIdx.x * 256 + threadIdx.x;   // < 4096*128
    unsigned int bits = mtb[idx];
    size_t base = (size_t)idx * 32;
    #pragma unroll
    for (int q = 0; q < 4; q++) {
        s16x8 v;
        #pragma unroll
        for (int e = 0; e < 8; e++)
            v[e] = (short)(((bits >> (q * 8 + e)) & 1u) ? 0x3F80 : 0);
        *(s16x8*)(MT + base + q * 8) = v;
    }
}

// ---------------- YT[c=b*128+f][i] = bf16( dinv_i * (x[b,i,:] @ W1[:,f]) ) ----------------
__global__ __launch_bounds__(256) void k_y1(
    const float* __restrict__ x, const float* __restrict__ W1,
    const float* __restrict__ dinv, unsigned short* __restrict__ YT)
{
    __shared__ __align__(16) float xs[128][DIN];
    __shared__ __align__(16) float w1s[DIN][DH];
    int i0 = blockIdx.x * 128, b = blockIdx.y;
    int tid = threadIdx.x;
    const f32x4* xg = (const f32x4*)(x + ((size_t)(b * NN + i0)) * DIN);
    #pragma unroll
    for (int q = 0; q < 8; q++) {
        int idx = q * 256 + tid;
        int row = idx >> 4, c4 = idx & 15;
        *(f32x4*)&xs[row][c4 * 4] = xg[(size_t)row * 16 + c4];
    }
    #pragma unroll
    for (int q = 0; q < 8; q++) {
        int idx = q * 256 + tid;
        int row = idx >> 5, c4 = idx & 31;
        *(f32x4*)&w1s[row][c4 * 4] = ((const f32x4*)W1)[idx];
    }
    __syncthreads();
    int tf = tid & 15, ti = tid >> 4;
    f32x4 t0[8] = {}, t1[8] = {};
    for (int k4 = 0; k4 < DIN; k4 += 4) {
        f32x4 xv[8];
        #pragma unroll
        for (int ii = 0; ii < 8; ii++) xv[ii] = *(const f32x4*)&xs[ti * 8 + ii][k4];
        #pragma unroll
        for (int kk = 0; kk < 4; kk++) {
            f32x4 w0 = *(const f32x4*)&w1s[k4 + kk][tf * 8];
            f32x4 w1v = *(const f32x4*)&w1s[k4 + kk][tf * 8 + 4];
            #pragma unroll
            for (int ii = 0; ii < 8; ii++) {
                float s = xv[ii][kk];
                t0[ii] += s * w0;
                t1[ii] += s * w1v;
            }
        }
    }
    float dvv[8];
    #pragma unroll
    for (int ii = 0; ii < 8; ii++) dvv[ii] = dinv[i0 + ti * 8 + ii];
    #pragma unroll
    for (int ff = 0; ff < 8; ff++) {
        s16x8 pk;
        #pragma unroll
        for (int ii = 0; ii < 8; ii++) {
            float v = (ff < 4 ? t0[ii][ff] : t1[ii][ff - 4]) * dvv[ii];
            pk[ii] = (short)f2bf(v);
        }
        *(s16x8*)(YT + ((size_t)(b * DH + tf * 8 + ff)) * NN + i0 + ti * 8) = pk;
    }
}

// ======== gemm1: 256x256 tile, BK=64, 8 waves, 8-phase counted-vmcnt ========
// C[j][c] = sum_i M[j][i] * YT[c][i];  H = bf16(relu(dinv_j*acc + bias[c&127]))
__global__ __launch_bounds__(512, 2) void gemm8(
    const unsigned short* __restrict__ A, const unsigned short* __restrict__ Bt,
    unsigned short* __restrict__ H, const float* __restrict__ dinv,
    const float* __restrict__ bias)
{
    constexpr int K = NN;          // 4096
    constexpr int NT = K / 64;     // 64 K-tiles
    __shared__ __align__(16) unsigned short As[2][256 * 64];   // 64 KB
    __shared__ __align__(16) unsigned short Bs[2][256 * 64];   // 64 KB

    const int tid = threadIdx.x;
    const int lane = tid & 63;
    const int w = tid >> 6;                 // wave 0..7
    const int wm = w >> 2, wn = w & 3;      // 2 x 4 wave grid
    const int fr = lane & 15, kg = lane >> 4;

    const int bid = blockIdx.x;             // 256 blocks, %8==0 -> simple XCD swizzle
    const int swz = (bid & 7) * 32 + (bid >> 3);
    const int bx = swz & 15, by = swz >> 4;
    const int c0 = bx * 256, j0 = by * 256;

    // staging: half-tile = 128 rows x 64 k = 1024 x 16B chunks; wave w covers
    // chunks [w*128, w*128+128), 2 gload16/thread. LDS linear, global pre-swizzled.
    const int cid0 = w * 128 + lane, cid1 = cid0 + 64;
    const int r0 = cid0 >> 3, k0c = cid0 & 7;
    const int r1 = cid1 >> 3, k1c = cid1 & 7;
    const int so0 = r0 * K + ((k0c ^ (r0 & 7)) << 3);   // ushort units
    const int so1 = r1 * K + ((k1c ^ (r1 & 7)) << 3);
    const int lb0 = (w * 2 + 0) * 512;                  // ushort units
    const int lb1 = (w * 2 + 1) * 512;

    const unsigned short* Aj = A + (size_t)j0 * K;
    const unsigned short* Bc = Bt + (size_t)c0 * K;

#define STAGE_A(buf, half, kt) do { \
    const unsigned short* g_ = Aj + (size_t)((half) * 128) * K + (kt); \
    gload16(g_ + so0, &As[buf][(half) * 8192 + lb0]); \
    gload16(g_ + so1, &As[buf][(half) * 8192 + lb1]); } while (0)
#define STAGE_B(buf, half, kt) do { \
    const unsigned short* g_ = Bc + (size_t)((half) * 128) * K + (kt); \
    gload16(g_ + so0, &Bs[buf][(half) * 8192 + lb0]); \
    gload16(g_ + so1, &Bs[buf][(half) * 8192 + lb1]); } while (0)

    // prologue: tile0 complete + tile1 {Ah0, Ah1, Bh0}  (7 half-tiles)
    STAGE_A(0, 0, 0);  STAGE_A(0, 1, 0);
    STAGE_B(0, 0, 0);  STAGE_B(0, 1, 0);
    STAGE_A(1, 0, 64); STAGE_A(1, 1, 64);
    STAGE_B(1, 0, 64);
    asm volatile("s_waitcnt vmcnt(6)" ::: "memory");   // tile0's 8 loads done
    bar();

    // frag addressing: row&7 == fr&7 for all frag rows -> xor is row-independent
    const int x0 = ((kg) ^ (fr & 7)) << 4;        // ks0 chunk, bytes
    const int x1 = ((4 + kg) ^ (fr & 7)) << 4;    // ks1 chunk, bytes
    int aOff[8], bOff[4];
    #pragma unroll
    for (int m = 0; m < 8; m++) aOff[m] = (wm * 128 + m * 16 + fr) * 128;
    #pragma unroll
    for (int n = 0; n < 4; n++) bOff[n] = (wn * 64 + n * 16 + fr) * 128;

    f32x4 acc[8][4] = {};

    for (int t = 0; t < NT; t++) {
        const int b = t & 1;
        const char* Ab = (const char*)As[b];
        const char* Bb = (const char*)Bs[b];
        const int kt1 = (t + 1) * 64, kt2 = (t + 2) * 64;
        const bool s1 = (t + 1) < NT, s2 = (t + 2) < NT;
        s16x8 af0[8], af1[8], bf0[4], bf1[4];

        // ---- P0: read ALL A frags + B ks0; stage B h1(t+1); mfma (ks0, m0-3)
        #pragma unroll
        for (int m = 0; m < 8; m++) {
            af0[m] = *(const s16x8*)(Ab + aOff[m] + x0);
            af1[m] = *(const s16x8*)(Ab + aOff[m] + x1);
        }
        #pragma unroll
        for (int n = 0; n < 4; n++) bf0[n] = *(const s16x8*)(Bb + bOff[n] + x0);
        if (s1) STAGE_B(b ^ 1, 1, kt1);
        bar();
        __builtin_amdgcn_s_setprio(1);
        #pragma unroll
        for (int m = 0; m < 4; m++)
            #pragma unroll
            for (int n = 0; n < 4; n++)
                acc[m][n] = __builtin_amdgcn_mfma_f32_16x16x32_bf16(af0[m], bf0[n], acc[m][n], 0, 0, 0);
        __builtin_amdgcn_s_setprio(0);
        bar();

        // ---- P1: read B ks1; stage A h0(t+2); mfma (ks0, m4-7)
        #pragma unroll
        for (int n = 0; n < 4; n++) bf1[n] = *(const s16x8*)(Bb + bOff[n] + x1);
        if (s2) STAGE_A(b, 0, kt2);
        bar();
        __builtin_amdgcn_s_setprio(1);
        #pragma unroll
        for (int m = 4; m < 8; m++)
            #pragma unroll
            for (int n = 0; n < 4; n++)
                acc[m][n] = __builtin_amdgcn_mfma_f32_16x16x32_bf16(af0[m], bf0[n], acc[m][n], 0, 0, 0);
        __builtin_amdgcn_s_setprio(0);
        bar();

        // ---- P2: stage A h1(t+2); mfma (ks1, m0-3)  [bf1 retired here]
        if (s2) STAGE_A(b, 1, kt2);
        bar();
        __builtin_amdgcn_s_setprio(1);
        #pragma unroll
        for (int m = 0; m < 4; m++)
            #pragma unroll
            for (int n = 0; n < 4; n++)
                acc[m][n] = __builtin_amdgcn_mfma_f32_16x16x32_bf16(af1[m], bf1[n], acc[m][n], 0, 0, 0);
        __builtin_amdgcn_s_setprio(0);
        bar();

        // ---- P3: stage B h0(t+2); counted vmcnt; mfma (ks1, m4-7)
        if (s2) STAGE_B(b, 0, kt2);
        if (s2) asm volatile("s_waitcnt vmcnt(6)" ::: "memory");
        else    asm volatile("s_waitcnt vmcnt(0)" ::: "memory");
        bar();
        __builtin_amdgcn_s_setprio(1);
        #pragma unroll
        for (int m = 4; m < 8; m++)
            #pragma unroll
            for (int n = 0; n < 4; n++)
                acc[m][n] = __builtin_amdgcn_mfma_f32_16x16x32_bf16(af1[m], bf1[n], acc[m][n], 0, 0, 0);
        __builtin_amdgcn_s_setprio(0);
        bar();
    }
#undef STAGE_A
#undef STAGE_B

    // epilogue: row = (lane>>4)*4 + r, col = lane&15 per 16x16 frag
    #pragma unroll
    for (int m = 0; m < 8; m++) {
        int rbase = j0 + wm * 128 + m * 16 + kg * 4;
        float dv[4];
        #pragma unroll
        for (int r = 0; r < 4; r++) dv[r] = dinv[rbase + r];
        #pragma unroll
        for (int n = 0; n < 4; n++) {
            int gcol = c0 + wn * 64 + n * 16 + fr;
            float bb = bias[gcol & (DH - 1)];
            #pragma unroll
            for (int r = 0; r < 4; r++) {
                float v = acc[m][n][r] * dv[r] + bb;
                v = v > 0.f ? v : 0.f;
                H[(size_t)(rbase + r) * NN + gcol] = f2bf(v);
            }
        }
    }
}

// ---------------- gemm2 (old 128x128 path): logits f32 = dinv_j*acc + bias ----------------
__global__ __launch_bounds__(256) void gemm_small(
    const unsigned short* __restrict__ A, const unsigned short* __restrict__ Bt,
    float* __restrict__ out, const float* __restrict__ dinv,
    const float* __restrict__ bias, int bmask, int N, int K)
{
    constexpr int BK = 64;
    __shared__ __align__(16) unsigned short Asm[128 * BK];
    __shared__ __align__(16) unsigned short Bsm[128 * BK];
    const int tid = threadIdx.x;
    const int lane = tid & 63;
    const int w = tid >> 6;
    const int wm = w >> 1, wn = w & 1;
    const int c0 = blockIdx.x * 128;
    const int j0 = blockIdx.y * 128;

    int srcOff[4];
    #pragma unroll
    for (int q = 0; q < 4; q++) {
        int cid = w * 256 + q * 64 + lane;
        int row = cid >> 3, kc = cid & 7;
        srcOff[q] = row * K + ((kc ^ (row & 7)) << 3);
    }
    const int fr = lane & 15;
    const int kg = lane >> 4;

    f32x4 acc[4][4] = {};
    const unsigned short* Abase = A + (size_t)j0 * K;
    const unsigned short* Bbase = Bt + (size_t)c0 * K;

    for (int kt = 0; kt < K; kt += BK) {
        __syncthreads();
        const unsigned short* Ag = Abase + kt;
        const unsigned short* Bg = Bbase + kt;
        #pragma unroll
        for (int q = 0; q < 4; q++)
            gload16(Ag + srcOff[q], &Asm[(w * 256 + q * 64) * 8]);
        #pragma unroll
        for (int q = 0; q < 4; q++)
            gload16(Bg + srcOff[q], &Bsm[(w * 256 + q * 64) * 8]);
        __syncthreads();

        s16x8 af[2][4], bf[2][4];
        #pragma unroll
        for (int ks = 0; ks < 2; ks++) {
            int kc = ks * 4 + kg;
            #pragma unroll
            for (int m = 0; m < 4; m++) {
                int row = wm * 64 + m * 16 + fr;
                af[ks][m] = *(const s16x8*)((const char*)Asm + row * 128 + ((kc ^ (row & 7)) << 4));
            }
            #pragma unroll
            for (int n = 0; n < 4; n++) {
                int row = wn * 64 + n * 16 + fr;
                bf[ks][n] = *(const s16x8*)((const char*)Bsm + row * 128 + ((kc ^ (row & 7)) << 4));
            }
        }
        #pragma unroll
        for (int ks = 0; ks < 2; ks++)
            #pragma unroll
            for (int m = 0; m < 4; m++)
                #pragma unroll
                for (int n = 0; n < 4; n++)
                    acc[m][n] = __builtin_amdgcn_mfma_f32_16x16x32_bf16(
                        af[ks][m], bf[ks][n], acc[m][n], 0, 0, 0);
    }

    #pragma unroll
    for (int m = 0; m < 4; m++) {
        int rbase = j0 + wm * 64 + m * 16 + kg * 4;
        float dv[4];
        #pragma unroll
        for (int r = 0; r < 4; r++) dv[r] = dinv[rbase + r];
        #pragma unroll
        for (int n = 0; n < 4; n++) {
            int gcol = c0 + wn * 64 + n * 16 + fr;
            float bb = bias[gcol & bmask];
            #pragma unroll
            for (int r = 0; r < 4; r++)
                out[(size_t)(rbase + r) * N + gcol] = acc[m][n][r] * dv[r] + bb;
        }
    }
}

// ---------------- ZT[c2=b*32+g][j] = bf16( dinv_j * (h[b,j,:] @ W2[:,g]) ) ----------------
__global__ __launch_bounds__(256) void k_z(
    const unsigned short* __restrict__ H, const float* __restrict__ W2,
    const float* __restrict__ dinv, unsigned short* __restrict__ ZT)
{
    __shared__ __align__(16) unsigned short Hs[128][136];
    __shared__ __align__(16) float w2s[DH][DOUT];
    int j0 = blockIdx.x * 128, b = blockIdx.y;
    int tid = threadIdx.x;
    #pragma unroll
    for (int q = 0; q < 8; q++) {
        int idx = q * 256 + tid;
        int row = idx >> 4, c = idx & 15;
        *(s16x8*)&Hs[row][c * 8] =
            *(const s16x8*)(H + (size_t)(j0 + row) * (NB * DH) + b * DH + c * 8);
    }
    #pragma unroll
    for (int q = 0; q < 4; q++) {
        int idx = q * 256 + tid;
        int row = idx >> 3, c4 = idx & 7;
        *(f32x4*)&w2s[row][c4 * 4] = ((const f32x4*)W2)[idx];
    }
    __syncthreads();
    int g = tid & 31, jq = tid >> 5;
    #pragma unroll
    for (int t = 0; t < 2; t++) {
        int jb = (t * 8 + jq) * 8;
        float accz[8] = {};
        for (int f8 = 0; f8 < 16; f8++) {
            float wv[8];
            #pragma unroll
            for (int e = 0; e < 8; e++) wv[e] = w2s[f8 * 8 + e][g];
            #pragma unroll
            for (int jj = 0; jj < 8; jj++) {
                s16x8 hc = *(const s16x8*)&Hs[jb + jj][f8 * 8];
                #pragma unroll
                for (int e = 0; e < 8; e++)
                    accz[jj] += bf2f((unsigned short)hc[e]) * wv[e];
            }
        }
        s16x8 pk;
        #pragma unroll
        for (int jj = 0; jj < 8; jj++)
            pk[jj] = (short)f2bf(accz[jj] * dinv[j0 + jb + jj]);
        *(s16x8*)(ZT + (size_t)(b * DOUT + g) * NN + j0 + jb) = pk;
    }
}

// ---------------- softmax over g, scatter to output layout ----------------
__global__ __launch_bounds__(256) void k_softmax(
    const float* __restrict__ logits, float* __restrict__ out)
{
    int tid = threadIdx.x;
    int p = blockIdx.x * 8 + (tid >> 5);        // p = b*4096 + j
    int b = p >> 12, j = p & 4095;
    int g = tid & 31;
    float v = logits[(size_t)j * (NB * DOUT) + b * DOUT + g];
    float m = v;
    #pragma unroll
    for (int d = 16; d; d >>= 1) m = fmaxf(m, __shfl_xor(m, d));
    float e = expf(v - m);
    float s = e;
    #pragma unroll
    for (int d = 16; d; d >>= 1) s += __shfl_xor(s, d);
    out[(size_t)p * DOUT + g] = e / s;
}

extern "C" void kernel_launch(void* const* d_in, const int* in_sizes, int n_in,
                              void* d_out, int out_size, void* d_ws, size_t ws_size,
                              hipStream_t stream)
{
    (void)in_sizes; (void)n_in; (void)out_size; (void)ws_size;
    const float* x    = (const float*)d_in[0];
    const float* emb1 = (const float*)d_in[1];
    const float* emb2 = (const float*)d_in[2];
    const float* l1w  = (const float*)d_in[3];
    const float* l1b  = (const float*)d_in[4];
    const float* l2w  = (const float*)d_in[5];
    const float* l2b  = (const float*)d_in[6];
    const float* g1w  = (const float*)d_in[7];
    const float* g1b  = (const float*)d_in[8];
    const float* g2w  = (const float*)d_in[9];
    const float* g2b  = (const float*)d_in[10];
    float* out = (float*)d_out;

    char* w = (char*)d_ws;
    float* n1 = (float*)w;                    w += NN * DIM * 4;
    float* n2 = (float*)w;                    w += NN * DIM * 4;
    int* deg = (int*)w;                       w += NN * 4;
    float* dinv = (float*)w;                  w += NN * 4;
    unsigned int* mtb = (unsigned int*)w;     w += (size_t)NN * 128 * 4;
    unsigned short* MT = (unsigned short*)w;  w += (size_t)NN * NN * 2;
    unsigned short* YT = (unsigned short*)w;  w += (size_t)NN * NN * 2;
    unsigned short* H  = (unsigned short*)w;  w += (size_t)NN * NN * 2;
    unsigned short* ZT = (unsigned short*)w;  w += (size_t)(NB * DOUT) * NN * 2;
    float* logits = (float*)YT;               // YT dead after gemm1

    hipMemsetAsync(deg, 0, NN * sizeof(int), stream);
    k_embed<<<1280, 256, 0, stream>>>(emb1, emb2, l1w, l1b, l2w, l2b, n1, n2);
    k_adj<<<dim3(64, 64), 256, 0, stream>>>(n1, n2, mtb, deg);
    k_dinv<<<16, 256, 0, stream>>>(deg, dinv);
    k_expand<<<2048, 256, 0, stream>>>(mtb, MT);
    k_y1<<<dim3(32, 32), 256, 0, stream>>>(x, g1w, dinv, YT);
    gemm8<<<256, 512, 0, stream>>>(MT, YT, H, dinv, g1b);
    k_z<<<dim3(32, 32), 256, 0, stream>>>(H, g2w, dinv, ZT);
    gemm_small<<<dim3(8, 32), 256, 0, stream>>>(MT, ZT, logits, dinv, g2b, 31,
                                                NB * DOUT, NN);
    k_softmax<<<16384, 256, 0, stream>>>(logits, out);
}

// Round 3
// 420.524 us; speedup vs baseline: 1.1206x; 1.0764x over previous
//
#include <hip/hip_runtime.h>

typedef float f32x4 __attribute__((ext_vector_type(4)));
typedef short s16x8 __attribute__((ext_vector_type(8)));

#define NN 4096
#define NB 32
#define DIN 64
#define DH 128
#define DOUT 32
#define DIM 40

__device__ __forceinline__ unsigned short f2bf(float f) {
    unsigned int u = __float_as_uint(f);
    unsigned int r = (u + 0x7FFFu + ((u >> 16) & 1u)) >> 16;
    return (unsigned short)r;
}
__device__ __forceinline__ float bf2f(unsigned short h) {
    return __uint_as_float(((unsigned int)h) << 16);
}
__device__ __forceinline__ void gload16(const void* g, void* l) {
    __builtin_amdgcn_global_load_lds(
        (const __attribute__((address_space(1))) unsigned int*)g,
        (__attribute__((address_space(3))) unsigned int*)l, 16, 0, 0);
}
__device__ __forceinline__ void bar() {
    asm volatile("" ::: "memory");
    __builtin_amdgcn_s_barrier();
    asm volatile("" ::: "memory");
}

// ---------------- stage 1: n1/n2 = tanh(3*(emb @ W + b)) ----------------
__global__ __launch_bounds__(256) void k_embed(
    const float* __restrict__ emb1, const float* __restrict__ emb2,
    const float* __restrict__ l1w, const float* __restrict__ l1b,
    const float* __restrict__ l2w, const float* __restrict__ l2b,
    float* __restrict__ n1, float* __restrict__ n2)
{
    __shared__ float w1s[DIM * DIM], w2s[DIM * DIM], b1s[DIM], b2s[DIM];
    int tid = threadIdx.x;
    for (int i = tid; i < DIM * DIM; i += 256) { w1s[i] = l1w[i]; w2s[i] = l2w[i]; }
    if (tid < DIM) { b1s[tid] = l1b[tid]; b2s[tid] = l2b[tid]; }
    __syncthreads();
    int t = blockIdx.x * 256 + tid;          // < 2*4096*40 = 327680
    int half = t >= NN * DIM;
    int r = t - half * (NN * DIM);
    int i = r / DIM, c = r - i * DIM;
    const float* emb = half ? emb2 : emb1;
    const float* ws  = half ? w2s : w1s;
    float acc = half ? b2s[c] : b1s[c];
    for (int k = 0; k < DIM; k++) acc += emb[i * DIM + k] * ws[k * DIM + c];
    (half ? n2 : n1)[r] = tanhf(3.0f * acc);
}

// ---------------- stage 2: adjacency bits + degree (register-tiled) ----------------
// Upper-triangle blocks only; each computes T1 = s[I,J], T2 = s[J,I] (fp32,
// register-tiled 4x4x2) and emits bits for BOTH orientations:
//   M[i0+p][j0+q] = T1[p][q] > T2[q][p]   (plus i==j self-loop on diag)
//   M[j0+p][i0+q] = T2[p][q] > T1[q][p]
#define APAD 44
#define TPAD 69
__global__ __launch_bounds__(256) void k_adj2(
    const float* __restrict__ n1, const float* __restrict__ n2,
    unsigned int* __restrict__ mtb, int* __restrict__ deg)
{
    const int bi = blockIdx.x, bj = blockIdx.y;
    if (bj < bi) return;
    const bool diag = (bi == bj);
    const int i0 = bi * 64, j0 = bj * 64;

    __shared__ __align__(16) float n1i[64 * APAD], n1j[64 * APAD];
    __shared__ __align__(16) float n2iT[DIM * 64], n2jT[DIM * 64];
    __shared__ float T1[64 * TPAD], T2[64 * TPAD];

    const int tid = threadIdx.x;
    // stage: n1 tiles row-major (coalesced global), n2 tiles transposed [k][col]
    for (int idx = tid; idx < 64 * DIM; idx += 256) {
        int r = idx / DIM, c = idx - r * DIM;
        n1i[r * APAD + c] = n1[(i0 + r) * DIM + c];
        n1j[r * APAD + c] = n1[(j0 + r) * DIM + c];
    }
    for (int idx = tid; idx < DIM * 64; idx += 256) {
        int k = idx >> 6, col = idx & 63;
        n2iT[k * 64 + col] = n2[(i0 + col) * DIM + k];
        n2jT[k * 64 + col] = n2[(j0 + col) * DIM + k];
    }
    __syncthreads();

    const int tq = tid & 15, tp = tid >> 4;
    const int rowb = tp * 4, colb = tq * 4;
    f32x4 acc1[4] = {}, acc2[4] = {};     // acc[di] = f32x4 over dq
    for (int k4 = 0; k4 < DIM; k4 += 4) {
        f32x4 a1[4], a2[4];
        #pragma unroll
        for (int di = 0; di < 4; di++) {
            a1[di] = *(const f32x4*)&n1i[(rowb + di) * APAD + k4];
            a2[di] = *(const f32x4*)&n1j[(rowb + di) * APAD + k4];
        }
        #pragma unroll
        for (int kk = 0; kk < 4; kk++) {
            f32x4 b2 = *(const f32x4*)&n2jT[(k4 + kk) * 64 + colb];
            f32x4 b1 = *(const f32x4*)&n2iT[(k4 + kk) * 64 + colb];
            #pragma unroll
            for (int di = 0; di < 4; di++) {
                acc1[di] += a1[di][kk] * b2;   // T1[p][q] = n1[I]·n2[J]
                acc2[di] += a2[di][kk] * b1;   // T2[p][q] = n1[J]·n2[I]
            }
        }
    }
    // spill tiles to LDS for the transpose-compare
    #pragma unroll
    for (int di = 0; di < 4; di++)
        #pragma unroll
        for (int dq = 0; dq < 4; dq++) {
            T1[(rowb + di) * TPAD + colb + dq] = acc1[di][dq];
            T2[(rowb + di) * TPAD + colb + dq] = acc2[di][dq];
        }
    __syncthreads();

    const int lane = tid & 63, w = tid >> 6;
    const int p = lane;
    #pragma unroll
    for (int qq = 0; qq < 16; qq++) {
        int q = w * 16 + qq;
        float t1  = T1[p * TPAD + q];     // s[i0+p][j0+q]
        float t2b = T2[q * TPAD + p];     // s[j0+q][i0+p]
        bool bit = (t1 > t2b) || (diag && p == q);
        unsigned long long mask = __ballot(bit);
        if (lane == 0) {
            mtb[(size_t)(j0 + q) * 128 + (i0 >> 5)]     = (unsigned int)mask;
            mtb[(size_t)(j0 + q) * 128 + (i0 >> 5) + 1] = (unsigned int)(mask >> 32);
            atomicAdd(&deg[j0 + q], (int)__popcll(mask));
        }
        if (!diag) {
            float t2  = T2[p * TPAD + q];     // s[j0+p][i0+q]
            float t1b = T1[q * TPAD + p];     // s[i0+q][j0+p]
            unsigned long long m2 = __ballot(t2 > t1b);
            if (lane == 0) {
                mtb[(size_t)(i0 + q) * 128 + (j0 >> 5)]     = (unsigned int)m2;
                mtb[(size_t)(i0 + q) * 128 + (j0 >> 5) + 1] = (unsigned int)(m2 >> 32);
                atomicAdd(&deg[i0 + q], (int)__popcll(m2));
            }
        }
    }
}

__global__ void k_dinv(const int* __restrict__ deg, float* __restrict__ dinv) {
    int i = blockIdx.x * 256 + threadIdx.x;
    if (i < NN) dinv[i] = 1.0f / sqrtf((float)deg[i]);
}

// bits -> bf16 0/1 matrix MT[j][i]
__global__ __launch_bounds__(256) void k_expand(
    const unsigned int* __restrict__ mtb, unsigned short* __restrict__ MT)
{
    int idx = blockIdx.x * 256 + threadIdx.x;   // < 4096*128
    unsigned int bits = mtb[idx];
    size_t base = (size_t)idx * 32;
    #pragma unroll
    for (int q = 0; q < 4; q++) {
        s16x8 v;
        #pragma unroll
        for (int e = 0; e < 8; e++)
            v[e] = (short)(((bits >> (q * 8 + e)) & 1u) ? 0x3F80 : 0);
        *(s16x8*)(MT + base + q * 8) = v;
    }
}

// ---------------- YT[c=b*128+f][i] = bf16( dinv_i * (x[b,i,:] @ W1[:,f]) ) ----------------
__global__ __launch_bounds__(256) void k_y1(
    const float* __restrict__ x, const float* __restrict__ W1,
    const float* __restrict__ dinv, unsigned short* __restrict__ YT)
{
    __shared__ __align__(16) float xs[128][DIN];
    __shared__ __align__(16) float w1s[DIN][DH];
    int i0 = blockIdx.x * 128, b = blockIdx.y;
    int tid = threadIdx.x;
    const f32x4* xg = (const f32x4*)(x + ((size_t)(b * NN + i0)) * DIN);
    #pragma unroll
    for (int q = 0; q < 8; q++) {
        int idx = q * 256 + tid;
        int row = idx >> 4, c4 = idx & 15;
        *(f32x4*)&xs[row][c4 * 4] = xg[(size_t)row * 16 + c4];
    }
    #pragma unroll
    for (int q = 0; q < 8; q++) {
        int idx = q * 256 + tid;
        int row = idx >> 5, c4 = idx & 31;
        *(f32x4*)&w1s[row][c4 * 4] = ((const f32x4*)W1)[idx];
    }
    __syncthreads();
    int tf = tid & 15, ti = tid >> 4;
    f32x4 t0[8] = {}, t1[8] = {};
    for (int k4 = 0; k4 < DIN; k4 += 4) {
        f32x4 xv[8];
        #pragma unroll
        for (int ii = 0; ii < 8; ii++) xv[ii] = *(const f32x4*)&xs[ti * 8 + ii][k4];
        #pragma unroll
        for (int kk = 0; kk < 4; kk++) {
            f32x4 w0 = *(const f32x4*)&w1s[k4 + kk][tf * 8];
            f32x4 w1v = *(const f32x4*)&w1s[k4 + kk][tf * 8 + 4];
            #pragma unroll
            for (int ii = 0; ii < 8; ii++) {
                float s = xv[ii][kk];
                t0[ii] += s * w0;
                t1[ii] += s * w1v;
            }
        }
    }
    float dvv[8];
    #pragma unroll
    for (int ii = 0; ii < 8; ii++) dvv[ii] = dinv[i0 + ti * 8 + ii];
    #pragma unroll
    for (int ff = 0; ff < 8; ff++) {
        s16x8 pk;
        #pragma unroll
        for (int ii = 0; ii < 8; ii++) {
            float v = (ff < 4 ? t0[ii][ff] : t1[ii][ff - 4]) * dvv[ii];
            pk[ii] = (short)f2bf(v);
        }
        *(s16x8*)(YT + ((size_t)(b * DH + tf * 8 + ff)) * NN + i0 + ti * 8) = pk;
    }
}

// ======== gemm1: 256x256 tile, BK=64, 8 waves, 8-phase counted-vmcnt ========
__global__ __launch_bounds__(512, 2) void gemm8(
    const unsigned short* __restrict__ A, const unsigned short* __restrict__ Bt,
    unsigned short* __restrict__ H, const float* __restrict__ dinv,
    const float* __restrict__ bias)
{
    constexpr int K = NN;          // 4096
    constexpr int NT = K / 64;     // 64 K-tiles
    __shared__ __align__(16) unsigned short As[2][256 * 64];   // 64 KB
    __shared__ __align__(16) unsigned short Bs[2][256 * 64];   // 64 KB

    const int tid = threadIdx.x;
    const int lane = tid & 63;
    const int w = tid >> 6;                 // wave 0..7
    const int wm = w >> 2, wn = w & 3;      // 2 x 4 wave grid
    const int fr = lane & 15, kg = lane >> 4;

    const int bid = blockIdx.x;             // 256 blocks, %8==0 -> simple XCD swizzle
    const int swz = (bid & 7) * 32 + (bid >> 3);
    const int bx = swz & 15, by = swz >> 4;
    const int c0 = bx * 256, j0 = by * 256;

    const int cid0 = w * 128 + lane, cid1 = cid0 + 64;
    const int r0 = cid0 >> 3, k0c = cid0 & 7;
    const int r1 = cid1 >> 3, k1c = cid1 & 7;
    const int so0 = r0 * K + ((k0c ^ (r0 & 7)) << 3);   // ushort units
    const int so1 = r1 * K + ((k1c ^ (r1 & 7)) << 3);
    const int lb0 = (w * 2 + 0) * 512;                  // ushort units
    const int lb1 = (w * 2 + 1) * 512;

    const unsigned short* Aj = A + (size_t)j0 * K;
    const unsigned short* Bc = Bt + (size_t)c0 * K;

#define STAGE_A(buf, half, kt) do { \
    const unsigned short* g_ = Aj + (size_t)((half) * 128) * K + (kt); \
    gload16(g_ + so0, &As[buf][(half) * 8192 + lb0]); \
    gload16(g_ + so1, &As[buf][(half) * 8192 + lb1]); } while (0)
#define STAGE_B(buf, half, kt) do { \
    const unsigned short* g_ = Bc + (size_t)((half) * 128) * K + (kt); \
    gload16(g_ + so0, &Bs[buf][(half) * 8192 + lb0]); \
    gload16(g_ + so1, &Bs[buf][(half) * 8192 + lb1]); } while (0)

    STAGE_A(0, 0, 0);  STAGE_A(0, 1, 0);
    STAGE_B(0, 0, 0);  STAGE_B(0, 1, 0);
    STAGE_A(1, 0, 64); STAGE_A(1, 1, 64);
    STAGE_B(1, 0, 64);
    asm volatile("s_waitcnt vmcnt(6)" ::: "memory");
    bar();

    const int x0 = ((kg) ^ (fr & 7)) << 4;
    const int x1 = ((4 + kg) ^ (fr & 7)) << 4;
    int aOff[8], bOff[4];
    #pragma unroll
    for (int m = 0; m < 8; m++) aOff[m] = (wm * 128 + m * 16 + fr) * 128;
    #pragma unroll
    for (int n = 0; n < 4; n++) bOff[n] = (wn * 64 + n * 16 + fr) * 128;

    f32x4 acc[8][4] = {};

    for (int t = 0; t < NT; t++) {
        const int b = t & 1;
        const char* Ab = (const char*)As[b];
        const char* Bb = (const char*)Bs[b];
        const int kt1 = (t + 1) * 64, kt2 = (t + 2) * 64;
        const bool s1 = (t + 1) < NT, s2 = (t + 2) < NT;
        s16x8 af0[8], af1[8], bf0[4], bf1[4];

        #pragma unroll
        for (int m = 0; m < 8; m++) {
            af0[m] = *(const s16x8*)(Ab + aOff[m] + x0);
            af1[m] = *(const s16x8*)(Ab + aOff[m] + x1);
        }
        #pragma unroll
        for (int n = 0; n < 4; n++) bf0[n] = *(const s16x8*)(Bb + bOff[n] + x0);
        if (s1) STAGE_B(b ^ 1, 1, kt1);
        bar();
        __builtin_amdgcn_s_setprio(1);
        #pragma unroll
        for (int m = 0; m < 4; m++)
            #pragma unroll
            for (int n = 0; n < 4; n++)
                acc[m][n] = __builtin_amdgcn_mfma_f32_16x16x32_bf16(af0[m], bf0[n], acc[m][n], 0, 0, 0);
        __builtin_amdgcn_s_setprio(0);
        bar();

        #pragma unroll
        for (int n = 0; n < 4; n++) bf1[n] = *(const s16x8*)(Bb + bOff[n] + x1);
        if (s2) STAGE_A(b, 0, kt2);
        bar();
        __builtin_amdgcn_s_setprio(1);
        #pragma unroll
        for (int m = 4; m < 8; m++)
            #pragma unroll
            for (int n = 0; n < 4; n++)
                acc[m][n] = __builtin_amdgcn_mfma_f32_16x16x32_bf16(af0[m], bf0[n], acc[m][n], 0, 0, 0);
        __builtin_amdgcn_s_setprio(0);
        bar();

        if (s2) STAGE_A(b, 1, kt2);
        bar();
        __builtin_amdgcn_s_setprio(1);
        #pragma unroll
        for (int m = 0; m < 4; m++)
            #pragma unroll
            for (int n = 0; n < 4; n++)
                acc[m][n] = __builtin_amdgcn_mfma_f32_16x16x32_bf16(af1[m], bf1[n], acc[m][n], 0, 0, 0);
        __builtin_amdgcn_s_setprio(0);
        bar();

        if (s2) STAGE_B(b, 0, kt2);
        if (s2) asm volatile("s_waitcnt vmcnt(6)" ::: "memory");
        else    asm volatile("s_waitcnt vmcnt(0)" ::: "memory");
        bar();
        __builtin_amdgcn_s_setprio(1);
        #pragma unroll
        for (int m = 4; m < 8; m++)
            #pragma unroll
            for (int n = 0; n < 4; n++)
                acc[m][n] = __builtin_amdgcn_mfma_f32_16x16x32_bf16(af1[m], bf1[n], acc[m][n], 0, 0, 0);
        __builtin_amdgcn_s_setprio(0);
        bar();
    }
#undef STAGE_A
#undef STAGE_B

    #pragma unroll
    for (int m = 0; m < 8; m++) {
        int rbase = j0 + wm * 128 + m * 16 + kg * 4;
        float dv[4];
        #pragma unroll
        for (int r = 0; r < 4; r++) dv[r] = dinv[rbase + r];
        #pragma unroll
        for (int n = 0; n < 4; n++) {
            int gcol = c0 + wn * 64 + n * 16 + fr;
            float bb = bias[gcol & (DH - 1)];
            #pragma unroll
            for (int r = 0; r < 4; r++) {
                float v = acc[m][n][r] * dv[r] + bb;
                v = v > 0.f ? v : 0.f;
                H[(size_t)(rbase + r) * NN + gcol] = f2bf(v);
            }
        }
    }
}

// ---------------- gemm2 (128x128 path): logits f32 = dinv_j*acc + bias ----------------
__global__ __launch_bounds__(256) void gemm_small(
    const unsigned short* __restrict__ A, const unsigned short* __restrict__ Bt,
    float* __restrict__ out, const float* __restrict__ dinv,
    const float* __restrict__ bias, int bmask, int N, int K)
{
    constexpr int BK = 64;
    __shared__ __align__(16) unsigned short Asm[128 * BK];
    __shared__ __align__(16) unsigned short Bsm[128 * BK];
    const int tid = threadIdx.x;
    const int lane = tid & 63;
    const int w = tid >> 6;
    const int wm = w >> 1, wn = w & 1;
    const int c0 = blockIdx.x * 128;
    const int j0 = blockIdx.y * 128;

    int srcOff[4];
    #pragma unroll
    for (int q = 0; q < 4; q++) {
        int cid = w * 256 + q * 64 + lane;
        int row = cid >> 3, kc = cid & 7;
        srcOff[q] = row * K + ((kc ^ (row & 7)) << 3);
    }
    const int fr = lane & 15;
    const int kg = lane >> 4;

    f32x4 acc[4][4] = {};
    const unsigned short* Abase = A + (size_t)j0 * K;
    const unsigned short* Bbase = Bt + (size_t)c0 * K;

    for (int kt = 0; kt < K; kt += BK) {
        __syncthreads();
        const unsigned short* Ag = Abase + kt;
        const unsigned short* Bg = Bbase + kt;
        #pragma unroll
        for (int q = 0; q < 4; q++)
            gload16(Ag + srcOff[q], &Asm[(w * 256 + q * 64) * 8]);
        #pragma unroll
        for (int q = 0; q < 4; q++)
            gload16(Bg + srcOff[q], &Bsm[(w * 256 + q * 64) * 8]);
        __syncthreads();

        s16x8 af[2][4], bf[2][4];
        #pragma unroll
        for (int ks = 0; ks < 2; ks++) {
            int kc = ks * 4 + kg;
            #pragma unroll
            for (int m = 0; m < 4; m++) {
                int row = wm * 64 + m * 16 + fr;
                af[ks][m] = *(const s16x8*)((const char*)Asm + row * 128 + ((kc ^ (row & 7)) << 4));
            }
            #pragma unroll
            for (int n = 0; n < 4; n++) {
                int row = wn * 64 + n * 16 + fr;
                bf[ks][n] = *(const s16x8*)((const char*)Bsm + row * 128 + ((kc ^ (row & 7)) << 4));
            }
        }
        #pragma unroll
        for (int ks = 0; ks < 2; ks++)
            #pragma unroll
            for (int m = 0; m < 4; m++)
                #pragma unroll
                for (int n = 0; n < 4; n++)
                    acc[m][n] = __builtin_amdgcn_mfma_f32_16x16x32_bf16(
                        af[ks][m], bf[ks][n], acc[m][n], 0, 0, 0);
    }

    #pragma unroll
    for (int m = 0; m < 4; m++) {
        int rbase = j0 + wm * 64 + m * 16 + kg * 4;
        float dv[4];
        #pragma unroll
        for (int r = 0; r < 4; r++) dv[r] = dinv[rbase + r];
        #pragma unroll
        for (int n = 0; n < 4; n++) {
            int gcol = c0 + wn * 64 + n * 16 + fr;
            float bb = bias[gcol & bmask];
            #pragma unroll
            for (int r = 0; r < 4; r++)
                out[(size_t)(rbase + r) * N + gcol] = acc[m][n][r] * dv[r] + bb;
        }
    }
}

// ---------------- ZT[c2=b*32+g][j] = bf16( dinv_j * (h[b,j,:] @ W2[:,g]) ) ----------------
__global__ __launch_bounds__(256) void k_z(
    const unsigned short* __restrict__ H, const float* __restrict__ W2,
    const float* __restrict__ dinv, unsigned short* __restrict__ ZT)
{
    __shared__ __align__(16) unsigned short Hs[128][136];
    __shared__ __align__(16) float w2s[DH][DOUT];
    int j0 = blockIdx.x * 128, b = blockIdx.y;
    int tid = threadIdx.x;
    #pragma unroll
    for (int q = 0; q < 8; q++) {
        int idx = q * 256 + tid;
        int row = idx >> 4, c = idx & 15;
        *(s16x8*)&Hs[row][c * 8] =
            *(const s16x8*)(H + (size_t)(j0 + row) * (NB * DH) + b * DH + c * 8);
    }
    #pragma unroll
    for (int q = 0; q < 4; q++) {
        int idx = q * 256 + tid;
        int row = idx >> 3, c4 = idx & 7;
        *(f32x4*)&w2s[row][c4 * 4] = ((const f32x4*)W2)[idx];
    }
    __syncthreads();
    int g = tid & 31, jq = tid >> 5;
    #pragma unroll
    for (int t = 0; t < 2; t++) {
        int jb = (t * 8 + jq) * 8;
        float accz[8] = {};
        for (int f8 = 0; f8 < 16; f8++) {
            float wv[8];
            #pragma unroll
            for (int e = 0; e < 8; e++) wv[e] = w2s[f8 * 8 + e][g];
            #pragma unroll
            for (int jj = 0; jj < 8; jj++) {
                s16x8 hc = *(const s16x8*)&Hs[jb + jj][f8 * 8];
                #pragma unroll
                for (int e = 0; e < 8; e++)
                    accz[jj] += bf2f((unsigned short)hc[e]) * wv[e];
            }
        }
        s16x8 pk;
        #pragma unroll
        for (int jj = 0; jj < 8; jj++)
            pk[jj] = (short)f2bf(accz[jj] * dinv[j0 + jb + jj]);
        *(s16x8*)(ZT + (size_t)(b * DOUT + g) * NN + j0 + jb) = pk;
    }
}

// ---------------- softmax over g, scatter to output layout ----------------
__global__ __launch_bounds__(256) void k_softmax(
    const float* __restrict__ logits, float* __restrict__ out)
{
    int tid = threadIdx.x;
    int p = blockIdx.x * 8 + (tid >> 5);        // p = b*4096 + j
    int b = p >> 12, j = p & 4095;
    int g = tid & 31;
    float v = logits[(size_t)j * (NB * DOUT) + b * DOUT + g];
    float m = v;
    #pragma unroll
    for (int d = 16; d; d >>= 1) m = fmaxf(m, __shfl_xor(m, d));
    float e = expf(v - m);
    float s = e;
    #pragma unroll
    for (int d = 16; d; d >>= 1) s += __shfl_xor(s, d);
    out[(size_t)p * DOUT + g] = e / s;
}

extern "C" void kernel_launch(void* const* d_in, const int* in_sizes, int n_in,
                              void* d_out, int out_size, void* d_ws, size_t ws_size,
                              hipStream_t stream)
{
    (void)in_sizes; (void)n_in; (void)out_size; (void)ws_size;
    const float* x    = (const float*)d_in[0];
    const float* emb1 = (const float*)d_in[1];
    const float* emb2 = (const float*)d_in[2];
    const float* l1w  = (const float*)d_in[3];
    const float* l1b  = (const float*)d_in[4];
    const float* l2w  = (const float*)d_in[5];
    const float* l2b  = (const float*)d_in[6];
    const float* g1w  = (const float*)d_in[7];
    const float* g1b  = (const float*)d_in[8];
    const float* g2w  = (const float*)d_in[9];
    const float* g2b  = (const float*)d_in[10];
    float* out = (float*)d_out;

    char* w = (char*)d_ws;
    float* n1 = (float*)w;                    w += NN * DIM * 4;
    float* n2 = (float*)w;                    w += NN * DIM * 4;
    int* deg = (int*)w;                       w += NN * 4;
    float* dinv = (float*)w;                  w += NN * 4;
    unsigned int* mtb = (unsigned int*)w;     w += (size_t)NN * 128 * 4;
    unsigned short* MT = (unsigned short*)w;  w += (size_t)NN * NN * 2;
    unsigned short* YT = (unsigned short*)w;  w += (size_t)NN * NN * 2;
    unsigned short* H  = (unsigned short*)w;  w += (size_t)NN * NN * 2;
    unsigned short* ZT = (unsigned short*)w;  w += (size_t)(NB * DOUT) * NN * 2;
    float* logits = (float*)YT;               // YT dead after gemm1

    hipMemsetAsync(deg, 0, NN * sizeof(int), stream);
    k_embed<<<1280, 256, 0, stream>>>(emb1, emb2, l1w, l1b, l2w, l2b, n1, n2);
    k_adj2<<<dim3(64, 64), 256, 0, stream>>>(n1, n2, mtb, deg);
    k_dinv<<<16, 256, 0, stream>>>(deg, dinv);
    k_expand<<<2048, 256, 0, stream>>>(mtb, MT);
    k_y1<<<dim3(32, 32), 256, 0, stream>>>(x, g1w, dinv, YT);
    gemm8<<<256, 512, 0, stream>>>(MT, YT, H, dinv, g1b);
    k_z<<<dim3(32, 32), 256, 0, stream>>>(H, g2w, dinv, ZT);
    gemm_small<<<dim3(8, 32), 256, 0, stream>>>(MT, ZT, logits, dinv, g2b, 31,
                                                NB * DOUT, NN);
    k_softmax<<<16384, 256, 0, stream>>>(logits, out);
}